// Round 3
// baseline (563.415 us; speedup 1.0000x reference)
//
#include <hip/hip_runtime.h>
#include <hip/hip_bf16.h>

typedef __hip_bfloat16 bf16t;

// Problem constants (fixed by setup_inputs; degree/alpha hardcoded from setup)
#define BB   32
#define NBB  10
#define VV1  3
#define VV2  3
#define SS   2
#define JJ   25
#define DINN 24
#define HH1  48
#define HH2  72
#define NF   256
#define NC   60
#define NROW (BB*NBB*VV1*VV2)   // 2880 instances (after s-mean)
#define EPSF 1e-5f
#define ALPHA 0.2f
#define DEG  4

// ws layout (bytes):
//  0    : int flag (1=bf16 inputs, 0=fp32)
//  256  : float M[625]
//  4096 : float pw[24228]  (W1,b1,g1,be1,W2,b2,g2,be2,W3,b3,g3,be3,bc)
//  101376: bf16 Wcp[384000] (M-folded, 0.5-scaled classifier weights)
#define WS_M_OFF    256
#define WS_PW_OFF   4096
#define WS_WCP_OFF  101376

// pw float offsets
#define P_W1  0
#define P_B1  1152
#define P_G1  1200
#define P_BE1 1248
#define P_W2  1296
#define P_B2  4752
#define P_G2  4824
#define P_BE2 4896
#define P_W3  4968
#define P_B3  23400
#define P_G3  23656
#define P_BE3 23912
#define P_BC  24168
#define P_TOT 24228

__device__ __forceinline__ float ldin(const void* p, int i, int isbf){
  return isbf ? __bfloat162float(((const bf16t*)p)[i]) : ((const float*)p)[i];
}
__device__ __forceinline__ void stout(void* p, int i, int isbf, float v){
  if(isbf) ((bf16t*)p)[i] = __float2bfloat16(v);
  else     ((float*)p)[i] = v;
}

// ---- kernel 0: dtype detect + build M = alpha*I + (1-alpha)/deg * sum_k A^k
__global__ void k0_prep(const void* x, const void* adj, int* flagp, float* M){
  __shared__ float A[625], P[625], Q[625], Ss[625];
  __shared__ int cnt, flg;
  int t = threadIdx.x;
  if(t==0) cnt = 0;
  __syncthreads();
  {
    // even-indexed 16-bit words: sane bf16 exponents iff data is bf16
    const unsigned short* xb = (const unsigned short*)x;
    unsigned short u = xb[2*t];
    int e = (u>>7)&0xFF;
    if(e>=100 && e<=141) atomicAdd(&cnt,1);
  }
  __syncthreads();
  if(t==0){ flg = (cnt>=160)?1:0; flagp[0]=flg; }
  __syncthreads();
  int isbf = flg;
  for(int i=t;i<625;i+=256){ float a=ldin(adj,i,isbf); A[i]=a; P[i]=a; Ss[i]=a; }
  __syncthreads();
  for(int d=1; d<DEG; ++d){
    for(int o=t;o<625;o+=256){
      int i=o/25, j=o%25; float acc=0.f;
      for(int k=0;k<25;k++) acc += A[i*25+k]*P[k*25+j];
      Q[o]=acc;
    }
    __syncthreads();
    for(int o=t;o<625;o+=256){ P[o]=Q[o]; Ss[o]+=Q[o]; }
    __syncthreads();
  }
  const float coef = (1.0f-ALPHA)/(float)DEG;
  for(int o=t;o<625;o+=256){
    int i=o/25, j=o%25;
    M[o] = (i==j ? ALPHA : 0.0f) + coef*Ss[o];
  }
}

// ---- kernel 1: repack all small params to fp32 in ws
__global__ void k1_repack(const void* W1,const void* b1,const void* g1,const void* be1,
                          const void* W2,const void* b2,const void* g2,const void* be2,
                          const void* W3,const void* b3,const void* g3,const void* be3,
                          const void* bc, const int* flagp, float* pw){
  int isbf = flagp[0];
  int o = blockIdx.x*256 + threadIdx.x;
  if(o >= P_TOT) return;
  const void* src; int loc;
  if      (o < P_B1 ) { src=W1;  loc=o;        }
  else if (o < P_G1 ) { src=b1;  loc=o-P_B1;   }
  else if (o < P_BE1) { src=g1;  loc=o-P_G1;   }
  else if (o < P_W2 ) { src=be1; loc=o-P_BE1;  }
  else if (o < P_B2 ) { src=W2;  loc=o-P_W2;   }
  else if (o < P_G2 ) { src=b2;  loc=o-P_B2;   }
  else if (o < P_BE2) { src=g2;  loc=o-P_G2;   }
  else if (o < P_W3 ) { src=be2; loc=o-P_BE2;  }
  else if (o < P_B3 ) { src=W3;  loc=o-P_W3;   }
  else if (o < P_G3 ) { src=b3;  loc=o-P_B3;   }
  else if (o < P_BE3) { src=g3;  loc=o-P_G3;   }   // FIXED: was o-P_BE3 (OOB)
  else if (o < P_BC ) { src=be3; loc=o-P_BE3;  }
  else                { src=bc;  loc=o-P_BC;   }
  pw[o] = ldin(src, loc, isbf);
}

// ---- kernel 2: fold SGC mix into classifier weights: Wcp[(j,f),c] = 0.5*sum_i M[i,j]*Wc[(i,f),c]
__global__ void k2_fold(const void* Wc, const float* M, const int* flagp, bf16t* Wcp){
  int isbf = flagp[0];
  int o = blockIdx.x*256 + threadIdx.x;   // grid covers exactly 384000
  if(o >= JJ*NF*NC) return;
  int k = o/NC, c = o - k*NC;
  int j = k/NF, f = k - j*NF;
  float acc = 0.f;
  for(int i=0;i<JJ;i++) acc += M[i*25+j]*ldin(Wc, (i*NF+f)*NC + c, isbf);
  Wcp[o] = __float2bfloat16(0.5f*acc);
}

// ---- kernel 3: per-(b,nb,v1,v2) fused MLP(+LN,ReLU) -> s-mean -> classifier -> block_mean
__global__ __launch_bounds__(256) void k3_main(const void* x, const float* pw,
                                               const bf16t* Wcp, const int* flagp,
                                               void* out){
  __shared__ float sm[10290];
  float* h3m = sm;          // 6400: sum over s of LN(h3)
  float* xs  = sm+6400;     // 600
  float* h1b = sm+7000;     // 1200
  float* h2b = sm+8200;     // 1800
  float* st  = sm+10000;    // 50: per-node mean,rstd
  float* cs  = sm+10050;    // 240: reduction scratch
  int t = threadIdx.x, bid = blockIdx.x;
  int isbf = flagp[0];
  const float* W1=pw+P_W1;  const float* b1=pw+P_B1;  const float* g1=pw+P_G1;  const float* be1=pw+P_BE1;
  const float* W2=pw+P_W2;  const float* b2=pw+P_B2;  const float* g2=pw+P_G2;  const float* be2=pw+P_BE2;
  const float* W3=pw+P_W3;  const float* b3=pw+P_B3;  const float* g3=pw+P_G3;  const float* be3=pw+P_BE3;
  const float* bc=pw+P_BC;

  for(int o=t;o<6400;o+=256) h3m[o]=0.f;

  for(int s=0;s<SS;s++){
    int xoff = bid*1200 + s*600;
    for(int i=t;i<600;i+=256) xs[i] = ldin(x, xoff+i, isbf);
    __syncthreads();
    // MLP1: [25,24] @ [24,48]
    for(int o=t;o<1200;o+=256){
      int n=o/48, c=o-(o/48)*48; float acc=b1[c];
      for(int k=0;k<24;k++) acc = fmaf(xs[n*24+k], W1[k*48+c], acc);
      h1b[o]=acc;
    }
    __syncthreads();
    if(t<25){
      float m=0.f; for(int k=0;k<48;k++) m+=h1b[t*48+k]; m*=(1.f/48.f);
      float v=0.f; for(int k=0;k<48;k++){ float d=h1b[t*48+k]-m; v=fmaf(d,d,v);} v*=(1.f/48.f);
      st[2*t]=m; st[2*t+1]=rsqrtf(v+EPSF);
    }
    __syncthreads();
    for(int o=t;o<1200;o+=256){
      int n=o/48, c=o-n*48;
      float val=(h1b[o]-st[2*n])*st[2*n+1]*g1[c]+be1[c];
      h1b[o]=fmaxf(val,0.f);
    }
    __syncthreads();
    // MLP2: [25,48] @ [48,72]
    for(int o=t;o<1800;o+=256){
      int n=o/72, c=o-n*72; float acc=b2[c];
      for(int k=0;k<48;k++) acc = fmaf(h1b[n*48+k], W2[k*72+c], acc);
      h2b[o]=acc;
    }
    __syncthreads();
    if(t<25){
      float m=0.f; for(int k=0;k<72;k++) m+=h2b[t*72+k]; m*=(1.f/72.f);
      float v=0.f; for(int k=0;k<72;k++){ float d=h2b[t*72+k]-m; v=fmaf(d,d,v);} v*=(1.f/72.f);
      st[2*t]=m; st[2*t+1]=rsqrtf(v+EPSF);
    }
    __syncthreads();
    for(int o=t;o<1800;o+=256){
      int n=o/72, c=o-n*72;
      float val=(h2b[o]-st[2*n])*st[2*n+1]*g2[c]+be2[c];
      h2b[o]=fmaxf(val,0.f);
    }
    __syncthreads();
    // MLP3: [25,72] @ [72,256]; c = t; 25 accumulators in registers.
    // Load each W3 row once per k (coalesced), broadcast h2 from LDS as float4.
    float acc3[25];
    #pragma unroll
    for(int n=0;n<25;n++) acc3[n]=b3[t];
    for(int k=0;k<72;k+=4){
      float w0=W3[(k+0)*256+t], w1=W3[(k+1)*256+t];
      float w2=W3[(k+2)*256+t], w3=W3[(k+3)*256+t];
      #pragma unroll
      for(int n=0;n<25;n++){
        float4 h = *reinterpret_cast<const float4*>(&h2b[n*72+k]);
        acc3[n]=fmaf(h.x,w0,acc3[n]); acc3[n]=fmaf(h.y,w1,acc3[n]);
        acc3[n]=fmaf(h.z,w2,acc3[n]); acc3[n]=fmaf(h.w,w3,acc3[n]);
      }
    }
    // LN over 256 (block-wide): wave shfl reduce + one LDS combine
    int lane = t&63, wid = t>>6;
    #pragma unroll
    for(int n=0;n<25;n++){
      float s1=acc3[n], s2=acc3[n]*acc3[n];
      for(int d=1;d<64;d<<=1){ s1+=__shfl_xor(s1,d,64); s2+=__shfl_xor(s2,d,64); }
      if(lane==0){ cs[n*8+2*wid]=s1; cs[n*8+2*wid+1]=s2; }
    }
    __syncthreads();
    #pragma unroll
    for(int n=0;n<25;n++){
      float S1=cs[n*8+0]+cs[n*8+2]+cs[n*8+4]+cs[n*8+6];
      float S2=cs[n*8+1]+cs[n*8+3]+cs[n*8+5]+cs[n*8+7];
      float m=S1*(1.f/256.f);
      float var=S2*(1.f/256.f)-m*m;
      float rstd=rsqrtf(var+EPSF);
      h3m[n*256+t] += (acc3[n]-m)*rstd*g3[t]+be3[t];
    }
    __syncthreads();
  }
  // classifier: block_mean[c] = sum_k h3m[k]*Wcp[k,c] + bc[c]
  // 240 threads = 4 k-chunks x 60 classes
  if(t<240){
    int kc=t/60, c=t-kc*60;
    float a0=0.f,a1=0.f,a2=0.f,a3=0.f;
    int k0=kc*1600;
    for(int k=k0;k<k0+1600;k+=4){
      a0=fmaf(h3m[k+0], __bfloat162float(Wcp[(k+0)*NC+c]), a0);
      a1=fmaf(h3m[k+1], __bfloat162float(Wcp[(k+1)*NC+c]), a1);
      a2=fmaf(h3m[k+2], __bfloat162float(Wcp[(k+2)*NC+c]), a2);
      a3=fmaf(h3m[k+3], __bfloat162float(Wcp[(k+3)*NC+c]), a3);
    }
    cs[t]=(a0+a1)+(a2+a3);
  }
  __syncthreads();
  if(t<60){
    float v = cs[t]+cs[60+t]+cs[120+t]+cs[180+t] + bc[t];
    stout(out, bid*NC+t, isbf, v);
  }
}

// ---- kernel 4: pred[b,c] = mean over 90 (nb,v1,v2) rows of block_mean
__global__ void k4_pred(const void* bm, const int* flagp, void* out){
  int b = blockIdx.x, t = threadIdx.x;
  int isbf = flagp[0];
  if(t<NC){
    float acc=0.f;
    for(int r=0;r<90;r++) acc += ldin(bm, (b*90+r)*NC+t, isbf);
    stout(out, NROW*NC + b*NC + t, isbf, acc*(1.f/90.f));
  }
}

extern "C" void kernel_launch(void* const* d_in, const int* in_sizes, int n_in,
                              void* d_out, int out_size, void* d_ws, size_t ws_size,
                              hipStream_t stream){
  const void* x   = d_in[0];
  const void* adj = d_in[1];
  char* ws = (char*)d_ws;
  int*   flagp = (int*)ws;
  float* M     = (float*)(ws + WS_M_OFF);
  float* pw    = (float*)(ws + WS_PW_OFF);
  bf16t* Wcp   = (bf16t*)(ws + WS_WCP_OFF);

  k0_prep<<<1,256,0,stream>>>(x, adj, flagp, M);
  k1_repack<<<(P_TOT+255)/256,256,0,stream>>>(d_in[2],d_in[3],d_in[4],d_in[5],
                                              d_in[6],d_in[7],d_in[8],d_in[9],
                                              d_in[10],d_in[11],d_in[12],d_in[13],
                                              d_in[15], flagp, pw);
  k2_fold<<<(JJ*NF*NC+255)/256,256,0,stream>>>(d_in[14], M, flagp, Wcp);
  k3_main<<<NROW,256,0,stream>>>(x, pw, Wcp, flagp, d_out);
  k4_pred<<<BB,64,0,stream>>>(d_out, flagp, d_out);
}

// Round 4
// 385.704 us; speedup vs baseline: 1.4607x; 1.4607x over previous
//
#include <hip/hip_runtime.h>
#include <hip/hip_bf16.h>

typedef __hip_bfloat16 bf16t;

#define BB   32
#define NBB  10
#define SS   2
#define JJ   25
#define NF   256
#define NC   60
#define NROW (BB*NBB*3*3)   // 2880 instances
#define EPSF 1e-5f
#define ALPHA 0.2f
#define DEG  4

// ws layout (bytes):
//  0     : int flag (1=bf16 inputs, 0=fp32)
//  256   : float M[625]
//  4096  : float pw[24228]
//  101376: bf16 Wcp2[384000] tiled [k/4][c][4]  (M-folded, 0.5-scaled)
#define WS_M_OFF    256
#define WS_PW_OFF   4096
#define WS_WCP_OFF  101376

// pw float offsets
#define P_W1  0
#define P_B1  1152
#define P_G1  1200
#define P_BE1 1248
#define P_W2  1296
#define P_B2  4752
#define P_G2  4824
#define P_BE2 4896
#define P_W3  4968
#define P_B3  23400
#define P_G3  23656
#define P_BE3 23912
#define P_BC  24168
#define P_TOT 24228

// k3 LDS float offsets
#define LDS_H3M 0        // 6400
#define LDS_H1B 6400     // 51*48 = 2448
#define LDS_B   8848     // 3672: xs[1200] then h2b[51*72]
#define LDS_ST  12520    // 100
#define LDS_CS  12620    // 240
#define LDS_TOT 12860    // 51440 B -> 3 blocks/CU

__device__ __forceinline__ float ldin(const void* p, int i, int isbf){
  return isbf ? __bfloat162float(((const bf16t*)p)[i]) : ((const float*)p)[i];
}
__device__ __forceinline__ void stout(void* p, int i, int isbf, float v){
  if(isbf) ((bf16t*)p)[i] = __float2bfloat16(v);
  else     ((float*)p)[i] = v;
}
__device__ __forceinline__ float bf2f(unsigned short u){
  unsigned int v = ((unsigned int)u)<<16; float f;
  __builtin_memcpy(&f,&v,4); return f;
}

// ---- kernel 0: dtype detect + M = alpha*I + (1-alpha)/deg * sum_k A^k
__global__ void k0_prep(const void* x, const void* adj, int* flagp, float* M){
  __shared__ float A[625], P[625], Q[625], Ss[625];
  __shared__ int cnt, flg;
  int t = threadIdx.x;
  if(t==0) cnt = 0;
  __syncthreads();
  {
    const unsigned short* xb = (const unsigned short*)x;
    unsigned short u = xb[2*t];
    int e = (u>>7)&0xFF;
    if(e>=100 && e<=141) atomicAdd(&cnt,1);
  }
  __syncthreads();
  if(t==0){ flg = (cnt>=160)?1:0; flagp[0]=flg; }
  __syncthreads();
  int isbf = flg;
  for(int i=t;i<625;i+=256){ float a=ldin(adj,i,isbf); A[i]=a; P[i]=a; Ss[i]=a; }
  __syncthreads();
  for(int d=1; d<DEG; ++d){
    for(int o=t;o<625;o+=256){
      int i=o/25, j=o%25; float acc=0.f;
      for(int k=0;k<25;k++) acc += A[i*25+k]*P[k*25+j];
      Q[o]=acc;
    }
    __syncthreads();
    for(int o=t;o<625;o+=256){ P[o]=Q[o]; Ss[o]+=Q[o]; }
    __syncthreads();
  }
  const float coef = (1.0f-ALPHA)/(float)DEG;
  for(int o=t;o<625;o+=256){
    int i=o/25, j=o%25;
    M[o] = (i==j ? ALPHA : 0.0f) + coef*Ss[o];
  }
}

// ---- kernel 1: repack small params to fp32
__global__ void k1_repack(const void* W1,const void* b1,const void* g1,const void* be1,
                          const void* W2,const void* b2,const void* g2,const void* be2,
                          const void* W3,const void* b3,const void* g3,const void* be3,
                          const void* bc, const int* flagp, float* pw){
  int isbf = flagp[0];
  int o = blockIdx.x*256 + threadIdx.x;
  if(o >= P_TOT) return;
  const void* src; int loc;
  if      (o < P_B1 ) { src=W1;  loc=o;        }
  else if (o < P_G1 ) { src=b1;  loc=o-P_B1;   }
  else if (o < P_BE1) { src=g1;  loc=o-P_G1;   }
  else if (o < P_W2 ) { src=be1; loc=o-P_BE1;  }
  else if (o < P_B2 ) { src=W2;  loc=o-P_W2;   }
  else if (o < P_G2 ) { src=b2;  loc=o-P_B2;   }
  else if (o < P_BE2) { src=g2;  loc=o-P_G2;   }
  else if (o < P_W3 ) { src=be2; loc=o-P_BE2;  }
  else if (o < P_B3 ) { src=W3;  loc=o-P_W3;   }
  else if (o < P_G3 ) { src=b3;  loc=o-P_B3;   }
  else if (o < P_BE3) { src=g3;  loc=o-P_G3;   }
  else if (o < P_BC ) { src=be3; loc=o-P_BE3;  }
  else                { src=bc;  loc=o-P_BC;   }
  pw[o] = ldin(src, loc, isbf);
}

// ---- kernel 2: fold SGC mix into classifier weights, tiled layout
// element o <-> (kt, c, kl): Wcp2[kt*240 + c*4 + kl] = 0.5*sum_i M[i,j]*Wc[(i*256+f)*60+c]
// with k = kt*4+kl, j = k/256, f = k%256
__global__ void k2_fold(const void* Wc, const float* M, const int* flagp, bf16t* Wcp){
  int isbf = flagp[0];
  int o = blockIdx.x*256 + threadIdx.x;
  if(o >= JJ*NF*NC) return;
  int kt = o/240, rem = o - kt*240;
  int c = rem>>2, kl = rem&3;
  int k = kt*4 + kl;
  int j = k>>8, f = k&255;
  float acc = 0.f;
  for(int i=0;i<25;i++) acc += M[i*25+j]*ldin(Wc, (i*256+f)*60 + c, isbf);
  Wcp[o] = __float2bfloat16(0.5f*acc);
}

// ---- kernel 3: fused MLP(+LN,ReLU) x3 -> s-mean -> classifier -> block_mean
__global__ __launch_bounds__(256) void k3_main(const void* x, const float* pw,
                                               const ushort4* Wcp2, const int* flagp,
                                               void* out){
  __shared__ float sm[LDS_TOT];
  float*  h3m  = sm + LDS_H3M;
  float*  h1b  = sm + LDS_H1B;
  float*  Bf   = sm + LDS_B;       // xs, then h2b
  float*  st   = sm + LDS_ST;
  float*  cs   = sm + LDS_CS;
  float4* h1b4 = (float4*)h1b;
  float4* Bf4  = (float4*)Bf;
  float4* h3m4 = (float4*)h3m;
  int t = threadIdx.x, bid = blockIdx.x;
  int isbf = flagp[0];
  const float* W1=pw+P_W1;  const float* b1=pw+P_B1;  const float* g1=pw+P_G1;  const float* be1=pw+P_BE1;
  const float* W2=pw+P_W2;  const float* b2=pw+P_B2;  const float* g2=pw+P_G2;  const float* be2=pw+P_BE2;
  const float* W3=pw+P_W3;  const float* b3=pw+P_B3;  const float* g3=pw+P_G3;  const float* be3=pw+P_BE3;
  const float* bc=pw+P_BC;

  for(int o=t;o<6400;o+=256) h3m[o]=0.f;
  // load x for both s: 50 rows x 24
  {
    int xoff = bid*1200;
    for(int i=t;i<1200;i+=256) Bf[i] = ldin(x, xoff+i, isbf);
  }
  __syncthreads();

  // ---- MLP1: [50,24]@[24,48]; 240 threads = 5 row-groups x 48 cols
  if(t<240){
    int g=t/48, c=t-g*48;
    float b1c=b1[c];
    float acc[10];
    #pragma unroll
    for(int q=0;q<10;q++) acc[q]=b1c;
    for(int k=0;k<24;k+=4){
      float w0=W1[(k+0)*48+c], w1=W1[(k+1)*48+c];
      float w2=W1[(k+2)*48+c], w3=W1[(k+3)*48+c];
      #pragma unroll
      for(int q=0;q<10;q++){
        float4 xv = Bf4[(g*10+q)*6 + (k>>2)];
        acc[q]=fmaf(xv.x,w0,acc[q]); acc[q]=fmaf(xv.y,w1,acc[q]);
        acc[q]=fmaf(xv.z,w2,acc[q]); acc[q]=fmaf(xv.w,w3,acc[q]);
      }
    }
    #pragma unroll
    for(int q=0;q<10;q++) h1b[(g*10+q)*48+c]=acc[q];
  }
  __syncthreads();
  // LN1 stats (50 rows over 48)
  if(t<50){
    float s1=0.f,s2=0.f;
    for(int i=0;i<12;i++){ float4 v=h1b4[t*12+i];
      s1+=v.x+v.y+v.z+v.w; s2+=v.x*v.x+v.y*v.y+v.z*v.z+v.w*v.w; }
    float m=s1*(1.f/48.f); float var=s2*(1.f/48.f)-m*m;
    st[2*t]=m; st[2*t+1]=rsqrtf(var+EPSF);
  }
  __syncthreads();
  // scale+ReLU, zero pad row 50
  for(int o=t;o<2448;o+=256){
    if(o<2400){
      int r=o/48, c=o-r*48;
      float val=(h1b[o]-st[2*r])*st[2*r+1]*g1[c]+be1[c];
      h1b[o]=fmaxf(val,0.f);
    } else h1b[o]=0.f;
  }
  __syncthreads();

  // ---- MLP2: [50,48]@[48,72]; 216 threads = 3 row-groups x 72 cols, rows r=g+3q
  if(t<216){
    int g=t/72, c=t-g*72;
    float b2c=b2[c];
    float acc[17];
    #pragma unroll
    for(int q=0;q<17;q++) acc[q]=b2c;
    for(int k=0;k<48;k+=4){
      float w0=W2[(k+0)*72+c], w1=W2[(k+1)*72+c];
      float w2=W2[(k+2)*72+c], w3=W2[(k+3)*72+c];
      #pragma unroll
      for(int q=0;q<17;q++){
        float4 xv = h1b4[(g+3*q)*12 + (k>>2)];
        acc[q]=fmaf(xv.x,w0,acc[q]); acc[q]=fmaf(xv.y,w1,acc[q]);
        acc[q]=fmaf(xv.z,w2,acc[q]); acc[q]=fmaf(xv.w,w3,acc[q]);
      }
    }
    #pragma unroll
    for(int q=0;q<17;q++) Bf[(g+3*q)*72+c]=acc[q];   // row 50 (g=2,q=16) is pad, fine
  }
  __syncthreads();
  // LN2 stats (50 rows over 72)
  if(t<50){
    float s1=0.f,s2=0.f;
    for(int i=0;i<18;i++){ float4 v=Bf4[t*18+i];
      s1+=v.x+v.y+v.z+v.w; s2+=v.x*v.x+v.y*v.y+v.z*v.z+v.w*v.w; }
    float m=s1*(1.f/72.f); float var=s2*(1.f/72.f)-m*m;
    st[2*t]=m; st[2*t+1]=rsqrtf(var+EPSF);
  }
  __syncthreads();
  for(int o=t;o<3600;o+=256){
    int r=o/72, c=o-r*72;
    float val=(Bf[o]-st[2*r])*st[2*r+1]*g2[c]+be2[c];
    Bf[o]=fmaxf(val,0.f);
  }
  __syncthreads();

  // ---- MLP3: [50,72]@[72,256]; col = t, 2 passes of 25 rows; LN over 256; h3m += (s-sum)
  float g3v=g3[t], be3v=be3[t], b3v=b3[t];
  int lane=t&63, wid=t>>6;
  for(int p=0;p<2;p++){
    float acc3[25];
    #pragma unroll
    for(int n=0;n<25;n++) acc3[n]=b3v;
    for(int k=0;k<72;k+=4){
      float w0=W3[(k+0)*256+t], w1=W3[(k+1)*256+t];
      float w2=W3[(k+2)*256+t], w3=W3[(k+3)*256+t];
      #pragma unroll
      for(int n=0;n<25;n++){
        float4 h = Bf4[(p*25+n)*18 + (k>>2)];
        acc3[n]=fmaf(h.x,w0,acc3[n]); acc3[n]=fmaf(h.y,w1,acc3[n]);
        acc3[n]=fmaf(h.z,w2,acc3[n]); acc3[n]=fmaf(h.w,w3,acc3[n]);
      }
    }
    #pragma unroll
    for(int n=0;n<25;n++){
      float s1=acc3[n], s2=acc3[n]*acc3[n];
      for(int d=1;d<64;d<<=1){ s1+=__shfl_xor(s1,d,64); s2+=__shfl_xor(s2,d,64); }
      if(lane==0){ cs[n*8+2*wid]=s1; cs[n*8+2*wid+1]=s2; }
    }
    __syncthreads();
    #pragma unroll
    for(int n=0;n<25;n++){
      float S1=cs[n*8+0]+cs[n*8+2]+cs[n*8+4]+cs[n*8+6];
      float S2=cs[n*8+1]+cs[n*8+3]+cs[n*8+5]+cs[n*8+7];
      float m=S1*(1.f/256.f);
      float var=S2*(1.f/256.f)-m*m;
      float rstd=rsqrtf(var+EPSF);
      h3m[n*256+t] += (acc3[n]-m)*rstd*g3v+be3v;
    }
    __syncthreads();
  }

  // ---- classifier: 240 threads = 4 k-chunks x 60 classes; vectorized+coalesced Wcp2
  if(t<240){
    int g=t/60, c=t-g*60;
    int kt0=g*400;
    float a0=0.f,a1=0.f,a2=0.f,a3=0.f;
    for(int i=0;i<400;i++){
      int kt=kt0+i;
      ushort4 wv = Wcp2[kt*60+c];
      float4  h  = h3m4[kt];
      a0=fmaf(h.x, bf2f(wv.x), a0);
      a1=fmaf(h.y, bf2f(wv.y), a1);
      a2=fmaf(h.z, bf2f(wv.z), a2);
      a3=fmaf(h.w, bf2f(wv.w), a3);
    }
    cs[t]=(a0+a1)+(a2+a3);
  }
  __syncthreads();
  if(t<60){
    float v = cs[t]+cs[60+t]+cs[120+t]+cs[180+t] + bc[t];
    stout(out, bid*NC+t, isbf, v);
  }
}

// ---- kernel 4: pred[b,c] = mean over 90 rows of block_mean
__global__ void k4_pred(const void* bm, const int* flagp, void* out){
  int b = blockIdx.x, t = threadIdx.x;
  int isbf = flagp[0];
  if(t<NC){
    float acc=0.f;
    for(int r=0;r<90;r++) acc += ldin(bm, (b*90+r)*NC+t, isbf);
    stout(out, NROW*NC + b*NC + t, isbf, acc*(1.f/90.f));
  }
}

extern "C" void kernel_launch(void* const* d_in, const int* in_sizes, int n_in,
                              void* d_out, int out_size, void* d_ws, size_t ws_size,
                              hipStream_t stream){
  const void* x   = d_in[0];
  const void* adj = d_in[1];
  char* ws = (char*)d_ws;
  int*    flagp = (int*)ws;
  float*  M     = (float*)(ws + WS_M_OFF);
  float*  pw    = (float*)(ws + WS_PW_OFF);
  bf16t*  Wcp   = (bf16t*)(ws + WS_WCP_OFF);

  k0_prep<<<1,256,0,stream>>>(x, adj, flagp, M);
  k1_repack<<<(P_TOT+255)/256,256,0,stream>>>(d_in[2],d_in[3],d_in[4],d_in[5],
                                              d_in[6],d_in[7],d_in[8],d_in[9],
                                              d_in[10],d_in[11],d_in[12],d_in[13],
                                              d_in[15], flagp, pw);
  k2_fold<<<(JJ*NF*NC+255)/256,256,0,stream>>>(d_in[14], M, flagp, Wcp);
  k3_main<<<NROW,256,0,stream>>>(x, pw, (const ushort4*)Wcp, flagp, d_out);
  k4_pred<<<BB,64,0,stream>>>(d_out, flagp, d_out);
}

// Round 6
// 271.628 us; speedup vs baseline: 2.0742x; 1.4200x over previous
//
#include <hip/hip_runtime.h>
#include <hip/hip_bf16.h>

typedef __hip_bfloat16 bf16t;
typedef __attribute__((ext_vector_type(8))) short short8v;  // 8 bf16 (4 VGPR)
typedef __attribute__((ext_vector_type(4))) float f32x4;

#define BB   32
#define NBB  10
#define JJ   25
#define NF   256
#define NC   60
#define NROW (BB*NBB*3*3)   // 2880 instances
#define EPSF 1e-5f
#define ALPHA 0.2f
#define DEG  4

// ws layout (bytes) — total footprint identical to proven round-3/4 (ends 869376):
//  0     : int flag
//  256   : float M[625]
//  4096  : float pw[5796]   (W1,b1,g1,be1,W2,b2,g2,be2,b3,g3,be3,bc — NO W3)
//  28672 : bf16 W3bf[24576] fragment-packed [ct][kt][lane][8], k-pad zeroed
//  101376: bf16 Wcp2[384000] tiled [k/4][c][4]
#define WS_M_OFF    256
#define WS_PW_OFF   4096
#define WS_W3BF_OFF 28672
#define WS_WCP_OFF  101376

// pw float offsets (W3 removed)
#define P_W1  0
#define P_B1  1152
#define P_G1  1200
#define P_BE1 1248
#define P_W2  1296
#define P_B2  4752
#define P_G2  4824
#define P_BE2 4896
#define P_B3  4968
#define P_G3  5224
#define P_BE3 5480
#define P_BC  5736
#define P_TOT 5796

// k3 LDS float offsets
#define LDS_H3M 0        // 6400
#define LDS_H1B 6400     // 2448 (51 rows x 48)
#define LDS_X   8848     // 3328: xs[1200] fp32, then A16 bf16 [64][104] ushort
#define LDS_STW 12176    // 512: per-wave row (s1,s2) x 64 rows x 4 waves
#define LDS_ST2 12688    // 128: per-row (m, rstd) for MLP3
#define LDS_ST  12816    // 100: LN1/LN2 stats
#define LDS_CS  12916    // 240
#define LDS_TOT 13156    // 52624 B -> 3 blocks/CU

__device__ __forceinline__ float ldin(const void* p, int i, int isbf){
  return isbf ? __bfloat162float(((const bf16t*)p)[i]) : ((const float*)p)[i];
}
__device__ __forceinline__ void stout(void* p, int i, int isbf, float v){
  if(isbf) ((bf16t*)p)[i] = __float2bfloat16(v);
  else     ((float*)p)[i] = v;
}
__device__ __forceinline__ float bf2f(unsigned short u){
  unsigned int v = ((unsigned int)u)<<16; float f;
  __builtin_memcpy(&f,&v,4); return f;
}

// ---- kernel 0: dtype detect + M = alpha*I + (1-alpha)/deg * sum_k A^k
__global__ void k0_prep(const void* x, const void* adj, int* flagp, float* M){
  __shared__ float A[625], P[625], Q[625], Ss[625];
  __shared__ int cnt, flg;
  int t = threadIdx.x;
  if(t==0) cnt = 0;
  __syncthreads();
  {
    const unsigned short* xb = (const unsigned short*)x;
    unsigned short u = xb[2*t];
    int e = (u>>7)&0xFF;
    if(e>=100 && e<=141) atomicAdd(&cnt,1);
  }
  __syncthreads();
  if(t==0){ flg = (cnt>=160)?1:0; flagp[0]=flg; }
  __syncthreads();
  int isbf = flg;
  for(int i=t;i<625;i+=256){ float a=ldin(adj,i,isbf); A[i]=a; P[i]=a; Ss[i]=a; }
  __syncthreads();
  for(int d=1; d<DEG; ++d){
    for(int o=t;o<625;o+=256){
      int i=o/25, j=o%25; float acc=0.f;
      for(int k=0;k<25;k++) acc += A[i*25+k]*P[k*25+j];
      Q[o]=acc;
    }
    __syncthreads();
    for(int o=t;o<625;o+=256){ P[o]=Q[o]; Ss[o]+=Q[o]; }
    __syncthreads();
  }
  const float coef = (1.0f-ALPHA)/(float)DEG;
  for(int o=t;o<625;o+=256){
    int i=o/25, j=o%25;
    M[o] = (i==j ? ALPHA : 0.0f) + coef*Ss[o];
  }
}

// ---- kernel 1: repack small params (minus W3) to fp32
__global__ void k1_repack(const void* W1,const void* b1,const void* g1,const void* be1,
                          const void* W2,const void* b2,const void* g2,const void* be2,
                          const void* b3,const void* g3,const void* be3,
                          const void* bc, const int* flagp, float* pw){
  int isbf = flagp[0];
  int o = blockIdx.x*256 + threadIdx.x;
  if(o >= P_TOT) return;
  const void* src; int loc;
  if      (o < P_B1 ) { src=W1;  loc=o;        }
  else if (o < P_G1 ) { src=b1;  loc=o-P_B1;   }
  else if (o < P_BE1) { src=g1;  loc=o-P_G1;   }
  else if (o < P_W2 ) { src=be1; loc=o-P_BE1;  }
  else if (o < P_B2 ) { src=W2;  loc=o-P_W2;   }
  else if (o < P_G2 ) { src=b2;  loc=o-P_B2;   }
  else if (o < P_BE2) { src=g2;  loc=o-P_G2;   }
  else if (o < P_B3 ) { src=be2; loc=o-P_BE2;  }
  else if (o < P_G3 ) { src=b3;  loc=o-P_B3;   }
  else if (o < P_BE3) { src=g3;  loc=o-P_G3;   }
  else if (o < P_BC ) { src=be3; loc=o-P_BE3;  }
  else                { src=bc;  loc=o-P_BC;   }
  pw[o] = ldin(src, loc, isbf);
}

// ---- kernel 1b: pack W3 (fp32/bf16 input) -> bf16 fragment layout
// W3bf[((ct*3+kt)*64+l)*8+j] = W3[k][col], k=kt*32+(l>>4)*8+j, col=ct*16+(l&15); 0 if k>=72
__global__ void k1b_packw3(const void* W3, const int* flagp, bf16t* W3bf){
  int isbf = flagp[0];
  int o = blockIdx.x*256 + threadIdx.x;
  if(o >= 24576) return;
  int ct = o/1536, rem = o - ct*1536;
  int kt = rem/512, rem2 = rem - kt*512;
  int l = rem2>>3, j = rem2&7;
  int k = kt*32 + ((l>>4)<<3) + j;
  int col = (ct<<4) + (l&15);
  float v = (k<72) ? ldin(W3, k*256+col, isbf) : 0.f;
  W3bf[o] = __float2bfloat16(v);
}

// ---- kernel 2: fold SGC mix into classifier weights, tiled [k/4][c][4]
__global__ void k2_fold(const void* Wc, const float* M, const int* flagp, bf16t* Wcp){
  int isbf = flagp[0];
  int o = blockIdx.x*256 + threadIdx.x;
  if(o >= JJ*NF*NC) return;
  int kt = o/240, rem = o - kt*240;
  int c = rem>>2, kl = rem&3;
  int k = kt*4 + kl;
  int j = k>>8, f = k&255;
  float acc = 0.f;
  for(int i=0;i<25;i++) acc += M[i*25+j]*ldin(Wc, (i*256+f)*60 + c, isbf);
  Wcp[o] = __float2bfloat16(0.5f*acc);
}

// ---- kernel 3: fused MLP1/2 (VALU) + MLP3 (MFMA bf16) + LNs -> s-mean -> classifier
__global__ __launch_bounds__(256) void k3_main(const void* x, const float* pw,
                                               const bf16t* W3bf_, const ushort4* Wcp2,
                                               const int* flagp, void* out){
  __shared__ float sm[LDS_TOT];
  float*  h3m  = sm + LDS_H3M;
  float*  h1b  = sm + LDS_H1B;
  float*  Xs   = sm + LDS_X;
  float*  stw  = sm + LDS_STW;
  float*  st2  = sm + LDS_ST2;
  float*  st   = sm + LDS_ST;
  float*  cs   = sm + LDS_CS;
  float4* h1b4 = (float4*)h1b;
  float4* Xs4  = (float4*)Xs;
  float4* h3m4 = (float4*)h3m;
  unsigned short* A16 = (unsigned short*)Xs;
  const unsigned short* W3bf = (const unsigned short*)W3bf_;

  int t = threadIdx.x, bid = blockIdx.x;
  int l = t&63, w = t>>6;
  int isbf = flagp[0];
  const float* W1=pw+P_W1;  const float* b1=pw+P_B1;  const float* g1=pw+P_G1;  const float* be1=pw+P_BE1;
  const float* W2=pw+P_W2;  const float* b2=pw+P_B2;  const float* g2=pw+P_G2;  const float* be2=pw+P_BE2;
  const float* b3=pw+P_B3;  const float* g3=pw+P_G3;  const float* be3=pw+P_BE3;
  const float* bc=pw+P_BC;

  // load x for both s: 50 rows x 24 fp32 into Xs
  {
    int xoff = bid*1200;
    for(int i=t;i<1200;i+=256) Xs[i] = ldin(x, xoff+i, isbf);
  }
  __syncthreads();

  // ---- MLP1: [50,24]@[24,48]; 240 threads = 5 row-groups x 48 cols
  if(t<240){
    int g=t/48, c=t-g*48;
    float b1c=b1[c];
    float acc[10];
    #pragma unroll
    for(int q=0;q<10;q++) acc[q]=b1c;
    for(int k=0;k<24;k+=4){
      float w0=W1[(k+0)*48+c], w1=W1[(k+1)*48+c];
      float w2=W1[(k+2)*48+c], w3=W1[(k+3)*48+c];
      #pragma unroll
      for(int q=0;q<10;q++){
        float4 xv = Xs4[(g*10+q)*6 + (k>>2)];
        acc[q]=fmaf(xv.x,w0,acc[q]); acc[q]=fmaf(xv.y,w1,acc[q]);
        acc[q]=fmaf(xv.z,w2,acc[q]); acc[q]=fmaf(xv.w,w3,acc[q]);
      }
    }
    #pragma unroll
    for(int q=0;q<10;q++) h1b[(g*10+q)*48+c]=acc[q];
  }
  __syncthreads();
  // LN1 stats + zero the X region (becomes bf16 A16 [64][104])
  if(t<50){
    float s1=0.f,s2=0.f;
    for(int i=0;i<12;i++){ float4 v=h1b4[t*12+i];
      s1+=v.x+v.y+v.z+v.w; s2+=v.x*v.x+v.y*v.y+v.z*v.z+v.w*v.w; }
    float m=s1*(1.f/48.f); float var=s2*(1.f/48.f)-m*m;
    st[2*t]=m; st[2*t+1]=rsqrtf(var+EPSF);
  }
  for(int o=t;o<3328;o+=256) Xs[o]=0.f;
  __syncthreads();
  // scale+ReLU h1, zero pad row 50
  for(int o=t;o<2448;o+=256){
    if(o<2400){
      int r=o/48, c=o-r*48;
      float val=(h1b[o]-st[2*r])*st[2*r+1]*g1[c]+be1[c];
      h1b[o]=fmaxf(val,0.f);
    } else h1b[o]=0.f;
  }
  __syncthreads();

  // ---- MLP2: [50,48]@[48,72] -> bf16 into A16 [row][104]
  if(t<216){
    int g=t/72, c=t-g*72;
    float b2c=b2[c];
    float acc[17];
    #pragma unroll
    for(int q=0;q<17;q++) acc[q]=b2c;
    for(int k=0;k<48;k+=4){
      float w0=W2[(k+0)*72+c], w1=W2[(k+1)*72+c];
      float w2=W2[(k+2)*72+c], w3=W2[(k+3)*72+c];
      #pragma unroll
      for(int q=0;q<17;q++){
        float4 xv = h1b4[(g+3*q)*12 + (k>>2)];
        acc[q]=fmaf(xv.x,w0,acc[q]); acc[q]=fmaf(xv.y,w1,acc[q]);
        acc[q]=fmaf(xv.z,w2,acc[q]); acc[q]=fmaf(xv.w,w3,acc[q]);
      }
    }
    #pragma unroll
    for(int q=0;q<17;q++){
      int r=g+3*q;                       // r=50 (g=2,q=16) is junk-but-finite pad
      A16[r*104+c] = (unsigned short)__bfloat16_as_ushort(__float2bfloat16(acc[q]));
    }
  }
  __syncthreads();
  // LN2 stats over bf16 h2 (rows 0..49, cols 0..71)
  if(t<50){
    float s1=0.f,s2=0.f;
    for(int k=0;k<72;k++){
      float v = bf2f(A16[t*104+k]);
      s1+=v; s2=fmaf(v,v,s2);
    }
    float m=s1*(1.f/72.f); float var=s2*(1.f/72.f)-m*m;
    st[2*t]=m; st[2*t+1]=rsqrtf(var+EPSF);
  }
  __syncthreads();
  // scale+ReLU in place (bf16)
  for(int o=t;o<3600;o+=256){
    int r=o/72, c=o-r*72;
    float val=(bf2f(A16[r*104+c])-st[2*r])*st[2*r+1]*g2[c]+be2[c];
    A16[r*104+c] = (unsigned short)__bfloat16_as_ushort(__float2bfloat16(fmaxf(val,0.f)));
  }
  __syncthreads();

  // ---- MLP3 via MFMA: [64(50 real),96(72 real)] @ [96,256], wave w owns cols 64w..64w+63
  f32x4 acc[4][4];
  float g3v[4], be3v[4];
  {
    #pragma unroll
    for(int nt=0;nt<4;nt++){
      int col = w*64 + nt*16 + (l&15);
      float b3c = b3[col];
      g3v[nt]=g3[col]; be3v[nt]=be3[col];
      #pragma unroll
      for(int mt=0;mt<4;mt++){ acc[mt][nt][0]=b3c; acc[mt][nt][1]=b3c; acc[mt][nt][2]=b3c; acc[mt][nt][3]=b3c; }
    }
  }
  {
    int arow = l&15, akg = (l>>4)<<3;
    #pragma unroll
    for(int kt=0;kt<3;kt++){
      short8v a[4];
      #pragma unroll
      for(int mt=0;mt<4;mt++)
        a[mt] = *(const short8v*)(A16 + (mt*16+arow)*104 + kt*32 + akg);
      #pragma unroll
      for(int nt=0;nt<4;nt++){
        int ct = w*4 + nt;
        short8v b = *(const short8v*)(W3bf + ((ct*3+kt)*64 + l)*8);
        #pragma unroll
        for(int mt=0;mt<4;mt++)
          acc[mt][nt] = __builtin_amdgcn_mfma_f32_16x16x32_bf16(a[mt], b, acc[mt][nt], 0,0,0);
      }
    }
  }
  // LN3 stats: per-row sums via 16-lane shfl reduce, cross-wave via stw
  #pragma unroll
  for(int mt=0;mt<4;mt++){
    #pragma unroll
    for(int r=0;r<4;r++){
      float s1 = acc[mt][0][r]+acc[mt][1][r]+acc[mt][2][r]+acc[mt][3][r];
      float s2 = acc[mt][0][r]*acc[mt][0][r]+acc[mt][1][r]*acc[mt][1][r]
               + acc[mt][2][r]*acc[mt][2][r]+acc[mt][3][r]*acc[mt][3][r];
      #pragma unroll
      for(int d=1;d<16;d<<=1){ s1+=__shfl_xor(s1,d,64); s2+=__shfl_xor(s2,d,64); }
      if((l&15)==0){
        int row = mt*16 + ((l>>4)<<2) + r;
        stw[row*8 + w*2]   = s1;
        stw[row*8 + w*2+1] = s2;
      }
    }
  }
  __syncthreads();
  if(t<64){
    float S1 = stw[t*8+0]+stw[t*8+2]+stw[t*8+4]+stw[t*8+6];
    float S2 = stw[t*8+1]+stw[t*8+3]+stw[t*8+5]+stw[t*8+7];
    float m = S1*(1.f/256.f);
    float var = S2*(1.f/256.f)-m*m;
    st2[2*t]=m; st2[2*t+1]=rsqrtf(var+EPSF);
  }
  __syncthreads();
  // pass A: rows 0..24 -> h3m = ln ; pass B: rows 25..49 -> h3m += ln
  #pragma unroll
  for(int mt=0;mt<2;mt++){
    #pragma unroll
    for(int r=0;r<4;r++){
      int row = mt*16 + ((l>>4)<<2) + r;
      if(row<25){
        float m=st2[2*row], rs=st2[2*row+1];
        #pragma unroll
        for(int nt=0;nt<4;nt++){
          int col = w*64 + nt*16 + (l&15);
          h3m[row*256+col] = (acc[mt][nt][r]-m)*rs*g3v[nt]+be3v[nt];
        }
      }
    }
  }
  __syncthreads();
  #pragma unroll
  for(int mt=1;mt<4;mt++){
    #pragma unroll
    for(int r=0;r<4;r++){
      int row = mt*16 + ((l>>4)<<2) + r;
      if(row>=25 && row<50){
        float m=st2[2*row], rs=st2[2*row+1];
        int jrow = row-25;
        #pragma unroll
        for(int nt=0;nt<4;nt++){
          int col = w*64 + nt*16 + (l&15);
          h3m[jrow*256+col] += (acc[mt][nt][r]-m)*rs*g3v[nt]+be3v[nt];
        }
      }
    }
  }
  __syncthreads();

  // ---- classifier: 240 threads = 4 k-chunks x 60 classes
  if(t<240){
    int g=t/60, c=t-g*60;
    int kt0=g*400;
    float a0=0.f,a1=0.f,a2=0.f,a3=0.f;
    for(int i=0;i<400;i++){
      int kt=kt0+i;
      ushort4 wv = Wcp2[kt*60+c];
      float4  h  = h3m4[kt];
      a0=fmaf(h.x, bf2f(wv.x), a0);
      a1=fmaf(h.y, bf2f(wv.y), a1);
      a2=fmaf(h.z, bf2f(wv.z), a2);
      a3=fmaf(h.w, bf2f(wv.w), a3);
    }
    cs[t]=(a0+a1)+(a2+a3);
  }
  __syncthreads();
  if(t<60){
    float v = cs[t]+cs[60+t]+cs[120+t]+cs[180+t] + bc[t];
    stout(out, bid*NC+t, isbf, v);
  }
}

// ---- kernel 4: pred[b,c] = mean over 90 rows of block_mean
__global__ void k4_pred(const void* bm, const int* flagp, void* out){
  int b = blockIdx.x, t = threadIdx.x;
  int isbf = flagp[0];
  if(t<NC){
    float acc=0.f;
    for(int r=0;r<90;r++) acc += ldin(bm, (b*90+r)*NC+t, isbf);
    stout(out, NROW*NC + b*NC + t, isbf, acc*(1.f/90.f));
  }
}

extern "C" void kernel_launch(void* const* d_in, const int* in_sizes, int n_in,
                              void* d_out, int out_size, void* d_ws, size_t ws_size,
                              hipStream_t stream){
  const void* x   = d_in[0];
  const void* adj = d_in[1];
  char* ws = (char*)d_ws;
  int*    flagp = (int*)ws;
  float*  M     = (float*)(ws + WS_M_OFF);
  float*  pw    = (float*)(ws + WS_PW_OFF);
  bf16t*  W3bf  = (bf16t*)(ws + WS_W3BF_OFF);
  bf16t*  Wcp   = (bf16t*)(ws + WS_WCP_OFF);

  k0_prep<<<1,256,0,stream>>>(x, adj, flagp, M);
  k1_repack<<<(P_TOT+255)/256,256,0,stream>>>(d_in[2],d_in[3],d_in[4],d_in[5],
                                              d_in[6],d_in[7],d_in[8],d_in[9],
                                              d_in[11],d_in[12],d_in[13],
                                              d_in[15], flagp, pw);
  k1b_packw3<<<96,256,0,stream>>>(d_in[10], flagp, W3bf);
  k2_fold<<<(JJ*NF*NC+255)/256,256,0,stream>>>(d_in[14], M, flagp, Wcp);
  k3_main<<<NROW,256,0,stream>>>(x, pw, W3bf, (const ushort4*)Wcp, flagp, d_out);
  k4_pred<<<BB,64,0,stream>>>(d_out, flagp, d_out);
}

// Round 8
// 175.929 us; speedup vs baseline: 3.2025x; 1.5440x over previous
//
#include <hip/hip_runtime.h>
#include <hip/hip_bf16.h>

typedef __hip_bfloat16 bf16t;
typedef _Float16 half_t;
typedef __attribute__((ext_vector_type(2))) _Float16 half2v;
typedef __attribute__((ext_vector_type(8))) _Float16 half8v;  // f16 MFMA A/B frag
typedef __attribute__((ext_vector_type(4))) float f32x4;

#define BB   32
#define NBB  10
#define JJ   25
#define NF   256
#define NC   60
#define NROW (BB*NBB*3*3)   // 2880 instances
#define EPSF 1e-5f
#define ALPHA 0.2f
#define DEG  4

// ws layout (bytes) — footprint identical to proven rounds (ends 869376):
//  0     : int flag
//  256   : float M[625]
//  4096  : float pw[5796]
//  28672 : f16 W3bf[24576]  fragment-packed [ct(16)][kt(3)][lane][8], k-pad zeroed
//  77824 : f16 W2bf[5120]   fragment-packed [ct(5)][kt(2)][lane][8], k/col-pad zeroed
//  101376: f16 Wcp4[384000] tiled [kt(1600)][cg(15)][p(2)][cl(4)][e(2)]
#define WS_M_OFF    256
#define WS_PW_OFF   4096
#define WS_W3BF_OFF 28672
#define WS_W2BF_OFF 77824
#define WS_WCP_OFF  101376

// pw float offsets
#define P_W1  0
#define P_B1  1152
#define P_G1  1200
#define P_BE1 1248
#define P_W2  1296
#define P_B2  4752
#define P_G2  4824
#define P_BE2 4896
#define P_B3  4968
#define P_G3  5224
#define P_BE3 5480
#define P_BC  5736
#define P_TOT 5796

// k3 LDS float offsets
#define LDS_H3M 0        // 6400
#define LDS_H1B 6400     // 2448 (51 rows x 48 fp32)
#define LDS_A1  8848     // 2304 f = f16 [64][72], 16B-aligned rows
#define LDS_A2  11152    // 3328 f = f16 [64][104]; doubles as fp32 x-stage (1200)
#define LDS_STW 14480    // 512: per-wave LN3 row partials
#define LDS_ST2 14992    // 128: LN3 (m,rstd)
#define LDS_ST  15120    // 100: LN1 stats
#define LDS_CS  15220    // 240
#define LDS_TOT 15460    // 61840 B -> 2 blocks/CU

__device__ __forceinline__ float ldin(const void* p, int i, int isbf){
  return isbf ? __bfloat162float(((const bf16t*)p)[i]) : ((const float*)p)[i];
}
__device__ __forceinline__ void stout(void* p, int i, int isbf, float v){
  if(isbf) ((bf16t*)p)[i] = __float2bfloat16(v);
  else     ((float*)p)[i] = v;
}
__device__ __forceinline__ half2v u2h2(unsigned int u){
  half2v h; __builtin_memcpy(&h,&u,4); return h;
}
__device__ __forceinline__ half2v pkh2(float a, float b){
  auto r = __builtin_amdgcn_cvt_pkrtz(a, b);   // __fp16 ext_vector(2)
  half2v h; __builtin_memcpy(&h,&r,4); return h;
}

// ---- kernel 0: dtype detect + M = alpha*I + (1-alpha)/deg * sum_k A^k
__global__ void k0_prep(const void* x, const void* adj, int* flagp, float* M){
  __shared__ float A[625], P[625], Q[625], Ss[625];
  __shared__ int cnt, flg;
  int t = threadIdx.x;
  if(t==0) cnt = 0;
  __syncthreads();
  {
    const unsigned short* xb = (const unsigned short*)x;
    unsigned short u = xb[2*t];
    int e = (u>>7)&0xFF;
    if(e>=100 && e<=141) atomicAdd(&cnt,1);
  }
  __syncthreads();
  if(t==0){ flg = (cnt>=160)?1:0; flagp[0]=flg; }
  __syncthreads();
  int isbf = flg;
  for(int i=t;i<625;i+=256){ float a=ldin(adj,i,isbf); A[i]=a; P[i]=a; Ss[i]=a; }
  __syncthreads();
  for(int d=1; d<DEG; ++d){
    for(int o=t;o<625;o+=256){
      int i=o/25, j=o%25; float acc=0.f;
      for(int k=0;k<25;k++) acc += A[i*25+k]*P[k*25+j];
      Q[o]=acc;
    }
    __syncthreads();
    for(int o=t;o<625;o+=256){ P[o]=Q[o]; Ss[o]+=Q[o]; }
    __syncthreads();
  }
  const float coef = (1.0f-ALPHA)/(float)DEG;
  for(int o=t;o<625;o+=256){
    int i=o/25, j=o%25;
    M[o] = (i==j ? ALPHA : 0.0f) + coef*Ss[o];
  }
}

// ---- kernel 1: repack small params to fp32
__global__ void k1_repack(const void* W1,const void* b1,const void* g1,const void* be1,
                          const void* W2,const void* b2,const void* g2,const void* be2,
                          const void* b3,const void* g3,const void* be3,
                          const void* bc, const int* flagp, float* pw){
  int isbf = flagp[0];
  int o = blockIdx.x*256 + threadIdx.x;
  if(o >= P_TOT) return;
  const void* src; int loc;
  if      (o < P_B1 ) { src=W1;  loc=o;        }
  else if (o < P_G1 ) { src=b1;  loc=o-P_B1;   }
  else if (o < P_BE1) { src=g1;  loc=o-P_G1;   }
  else if (o < P_W2 ) { src=be1; loc=o-P_BE1;  }
  else if (o < P_B2 ) { src=W2;  loc=o-P_W2;   }
  else if (o < P_G2 ) { src=b2;  loc=o-P_B2;   }
  else if (o < P_BE2) { src=g2;  loc=o-P_G2;   }
  else if (o < P_B3 ) { src=be2; loc=o-P_BE2;  }
  else if (o < P_G3 ) { src=b3;  loc=o-P_B3;   }
  else if (o < P_BE3) { src=g3;  loc=o-P_G3;   }
  else if (o < P_BC ) { src=be3; loc=o-P_BE3;  }
  else                { src=bc;  loc=o-P_BC;   }
  pw[o] = ldin(src, loc, isbf);
}

// ---- kernel 1b: pack W3 -> f16 fragment layout (16 ct x 3 kt)
__global__ void k1b_packw3(const void* W3, const int* flagp, half_t* W3bf){
  int isbf = flagp[0];
  int o = blockIdx.x*256 + threadIdx.x;
  if(o >= 24576) return;
  int ct = o/1536, rem = o - ct*1536;
  int kt = rem/512, rem2 = rem - kt*512;
  int l = rem2>>3, j = rem2&7;
  int k = kt*32 + ((l>>4)<<3) + j;
  int col = (ct<<4) + (l&15);
  float v = (k<72) ? ldin(W3, k*256+col, isbf) : 0.f;
  W3bf[o] = (half_t)v;
}

// ---- kernel 1c: pack W2 -> f16 fragment layout (5 ct x 2 kt), pads zeroed
__global__ void k1c_packw2(const void* W2, const int* flagp, half_t* W2bf){
  int isbf = flagp[0];
  int o = blockIdx.x*256 + threadIdx.x;
  if(o >= 5120) return;
  int ct = o/1024, rem = o - ct*1024;
  int kt = rem/512, rem2 = rem - kt*512;
  int l = rem2>>3, j = rem2&7;
  int k = kt*32 + ((l>>4)<<3) + j;
  int col = (ct<<4) + (l&15);
  float v = (k<48 && col<72) ? ldin(W2, k*72+col, isbf) : 0.f;
  W2bf[o] = (half_t)v;
}

// ---- kernel 2: fold SGC mix into classifier weights, f16, dot2-tiled
// o = (kt*15+cg)*16 + hw; hw = p*8 + cl*2 + e; kl = 2p+e; fl = 4kt+kl; c = 4cg+cl
__global__ void k2_fold(const void* Wc, const float* M, const int* flagp, half_t* Wcp4){
  int isbf = flagp[0];
  int o = blockIdx.x*256 + threadIdx.x;
  if(o >= 384000) return;
  int grp = o>>4, hw = o&15;
  int kt = grp/15, cg = grp - kt*15;
  int p = hw>>3, cl = (hw>>1)&3, e = hw&1;
  int fl = kt*4 + 2*p + e;
  int j = fl>>8, f = fl&255;
  int c = cg*4 + cl;
  float acc = 0.f;
  for(int i=0;i<25;i++) acc += M[i*25+j]*ldin(Wc, (i*256+f)*60 + c, isbf);
  Wcp4[o] = (half_t)(0.5f*acc);
}

// ---- kernel 3: MLP1(VALU) + MFMA2 + MFMA3 (f16) + LNs -> s-mean -> dot2 classifier
__global__ __launch_bounds__(256) void k3_main(const void* x, const float* pw,
                                               const half_t* W3bf_, const half_t* W2bf_,
                                               const unsigned short* Wcp4,
                                               const int* flagp, void* out){
  __shared__ float sm[LDS_TOT];
  float*  h3m  = sm + LDS_H3M;
  float*  h1b  = sm + LDS_H1B;
  float*  Xs   = sm + LDS_A2;      // fp32 x-stage lives in A2 region
  float*  stw  = sm + LDS_STW;
  float*  st2  = sm + LDS_ST2;
  float*  st   = sm + LDS_ST;
  float*  cs   = sm + LDS_CS;
  float4* h1b4 = (float4*)h1b;
  float4* Xs4  = (float4*)Xs;
  float4* h3m4 = (float4*)h3m;
  unsigned short* A1u = (unsigned short*)(sm + LDS_A1);  // f16 [64][72]
  unsigned short* A2u = (unsigned short*)(sm + LDS_A2);  // f16 [64][104]
  const unsigned short* W3u = (const unsigned short*)W3bf_;
  const unsigned short* W2u = (const unsigned short*)W2bf_;

  int t = threadIdx.x, bid = blockIdx.x;
  int l = t&63, w = t>>6;
  int isbf = flagp[0];
  const float* W1=pw+P_W1;  const float* b1=pw+P_B1;  const float* g1=pw+P_G1;  const float* be1=pw+P_BE1;
  const float* b2=pw+P_B2;  const float* g2=pw+P_G2;  const float* be2=pw+P_BE2;
  const float* b3=pw+P_B3;  const float* g3=pw+P_G3;  const float* be3=pw+P_BE3;
  const float* bc=pw+P_BC;

  // stage x (both s: 50 rows x 24) fp32; zero A1
  {
    int xoff = bid*1200;
    for(int i=t;i<1200;i+=256) Xs[i] = ldin(x, xoff+i, isbf);
    for(int o=t;o<2304;o+=256) sm[LDS_A1+o] = 0.f;
  }
  __syncthreads();

  // ---- MLP1: [50,24]@[24,48]; 240 threads = 5 row-groups x 48 cols
  if(t<240){
    int g=t/48, c=t-g*48;
    float b1c=b1[c];
    float acc[10];
    #pragma unroll
    for(int q=0;q<10;q++) acc[q]=b1c;
    for(int k=0;k<24;k+=4){
      float w0=W1[(k+0)*48+c], w1=W1[(k+1)*48+c];
      float w2=W1[(k+2)*48+c], w3=W1[(k+3)*48+c];
      #pragma unroll
      for(int q=0;q<10;q++){
        float4 xv = Xs4[(g*10+q)*6 + (k>>2)];
        acc[q]=fmaf(xv.x,w0,acc[q]); acc[q]=fmaf(xv.y,w1,acc[q]);
        acc[q]=fmaf(xv.z,w2,acc[q]); acc[q]=fmaf(xv.w,w3,acc[q]);
      }
    }
    #pragma unroll
    for(int q=0;q<10;q++) h1b[(g*10+q)*48+c]=acc[q];
  }
  __syncthreads();
  // LN1 stats (50 rows over 48)
  if(t<50){
    float s1=0.f,s2=0.f;
    for(int i=0;i<12;i++){ float4 v=h1b4[t*12+i];
      s1+=v.x+v.y+v.z+v.w; s2+=v.x*v.x+v.y*v.y+v.z*v.z+v.w*v.w; }
    float m=s1*(1.f/48.f); float var=s2*(1.f/48.f)-m*m;
    st[2*t]=m; st[2*t+1]=rsqrtf(var+EPSF);
  }
  __syncthreads();
  // scale+ReLU -> A1 f16 (rows<50, cols<48); zero A2 (x consumed)
  for(int o=t;o<2400;o+=256){
    int r=o/48, c=o-r*48;
    float val=(h1b[o]-st[2*r])*st[2*r+1]*g1[c]+be1[c];
    ((half_t*)A1u)[r*72+c] = (half_t)fmaxf(val,0.f);
  }
  for(int o=t;o<3328;o+=256) sm[LDS_A2+o] = 0.f;
  __syncthreads();

  // ---- MFMA2: [64(50),80(72)] @ [72->64,80]; M-split: wave w owns rows 16w..16w+15
  {
    int arow = l&15, akg = (l>>4)<<3;
    int colb = l&15;
    f32x4 acc2[5];
    #pragma unroll
    for(int ct=0;ct<5;ct++){
      int col = ct*16 + colb;
      float b2c = (col<72) ? b2[col] : 0.f;
      acc2[ct][0]=b2c; acc2[ct][1]=b2c; acc2[ct][2]=b2c; acc2[ct][3]=b2c;
    }
    #pragma unroll
    for(int kt=0;kt<2;kt++){
      half8v a = *(const half8v*)(A1u + (w*16+arow)*72 + kt*32 + akg);
      #pragma unroll
      for(int ct=0;ct<5;ct++){
        half8v b = *(const half8v*)(W2u + ((ct*2+kt)*64 + l)*8);
        acc2[ct] = __builtin_amdgcn_mfma_f32_16x16x32_f16(a, b, acc2[ct], 0,0,0);
      }
    }
    // LN2: wave-local row stats (rows 16w + (l>>4)*4 + r), reduce across 16 col-lanes
    int valid4 = (colb<8);
    #pragma unroll
    for(int r=0;r<4;r++){
      float s1 = acc2[0][r]+acc2[1][r]+acc2[2][r]+acc2[3][r] + (valid4?acc2[4][r]:0.f);
      float s2 = acc2[0][r]*acc2[0][r]+acc2[1][r]*acc2[1][r]
               + acc2[2][r]*acc2[2][r]+acc2[3][r]*acc2[3][r]
               + (valid4?acc2[4][r]*acc2[4][r]:0.f);
      #pragma unroll
      for(int d=1;d<16;d<<=1){ s1+=__shfl_xor(s1,d,64); s2+=__shfl_xor(s2,d,64); }
      float m = s1*(1.f/72.f);
      float var = s2*(1.f/72.f)-m*m;
      float rs = rsqrtf(var+EPSF);
      int grow = w*16 + ((l>>4)<<2) + r;
      #pragma unroll
      for(int ct=0;ct<5;ct++){
        int col = ct*16 + colb;
        if(ct<4 || valid4){
          float val = (acc2[ct][r]-m)*rs*g2[col]+be2[col];
          ((half_t*)A2u)[grow*104+col] = (half_t)fmaxf(val,0.f);
        }
      }
    }
  }
  __syncthreads();

  // ---- MFMA3: [64(50),96(72)] @ [96,256]; N-split: wave w owns cols 64w..64w+63
  f32x4 acc[4][4];
  float g3v[4], be3v[4];
  {
    #pragma unroll
    for(int nt=0;nt<4;nt++){
      int col = w*64 + nt*16 + (l&15);
      float b3c = b3[col];
      g3v[nt]=g3[col]; be3v[nt]=be3[col];
      #pragma unroll
      for(int mt=0;mt<4;mt++){ acc[mt][nt][0]=b3c; acc[mt][nt][1]=b3c; acc[mt][nt][2]=b3c; acc[mt][nt][3]=b3c; }
    }
  }
  {
    int arow = l&15, akg = (l>>4)<<3;
    #pragma unroll
    for(int kt=0;kt<3;kt++){
      half8v a[4];
      #pragma unroll
      for(int mt=0;mt<4;mt++)
        a[mt] = *(const half8v*)(A2u + (mt*16+arow)*104 + kt*32 + akg);
      #pragma unroll
      for(int nt=0;nt<4;nt++){
        int ct = w*4 + nt;
        half8v b = *(const half8v*)(W3u + ((ct*3+kt)*64 + l)*8);
        #pragma unroll
        for(int mt=0;mt<4;mt++)
          acc[mt][nt] = __builtin_amdgcn_mfma_f32_16x16x32_f16(a[mt], b, acc[mt][nt], 0,0,0);
      }
    }
  }
  // LN3 stats: 16-lane shfl reduce, cross-wave via stw
  #pragma unroll
  for(int mt=0;mt<4;mt++){
    #pragma unroll
    for(int r=0;r<4;r++){
      float s1 = acc[mt][0][r]+acc[mt][1][r]+acc[mt][2][r]+acc[mt][3][r];
      float s2 = acc[mt][0][r]*acc[mt][0][r]+acc[mt][1][r]*acc[mt][1][r]
               + acc[mt][2][r]*acc[mt][2][r]+acc[mt][3][r]*acc[mt][3][r];
      #pragma unroll
      for(int d=1;d<16;d<<=1){ s1+=__shfl_xor(s1,d,64); s2+=__shfl_xor(s2,d,64); }
      if((l&15)==0){
        int row = mt*16 + ((l>>4)<<2) + r;
        stw[row*8 + w*2]   = s1;
        stw[row*8 + w*2+1] = s2;
      }
    }
  }
  __syncthreads();
  if(t<64){
    float S1 = stw[t*8+0]+stw[t*8+2]+stw[t*8+4]+stw[t*8+6];
    float S2 = stw[t*8+1]+stw[t*8+3]+stw[t*8+5]+stw[t*8+7];
    float m = S1*(1.f/256.f);
    float var = S2*(1.f/256.f)-m*m;
    st2[2*t]=m; st2[2*t+1]=rsqrtf(var+EPSF);
  }
  __syncthreads();
  // pass A: rows 0..24 -> h3m = ln
  #pragma unroll
  for(int mt=0;mt<2;mt++){
    #pragma unroll
    for(int r=0;r<4;r++){
      int row = mt*16 + ((l>>4)<<2) + r;
      if(row<25){
        float m=st2[2*row], rs=st2[2*row+1];
        #pragma unroll
        for(int nt=0;nt<4;nt++){
          int col = w*64 + nt*16 + (l&15);
          h3m[row*256+col] = (acc[mt][nt][r]-m)*rs*g3v[nt]+be3v[nt];
        }
      }
    }
  }
  __syncthreads();
  // pass B: rows 25..49 -> h3m += ln
  #pragma unroll
  for(int mt=1;mt<4;mt++){
    #pragma unroll
    for(int r=0;r<4;r++){
      int row = mt*16 + ((l>>4)<<2) + r;
      if(row>=25 && row<50){
        float m=st2[2*row], rs=st2[2*row+1];
        int jrow = row-25;
        #pragma unroll
        for(int nt=0;nt<4;nt++){
          int col = w*64 + nt*16 + (l&15);
          h3m[jrow*256+col] += (acc[mt][nt][r]-m)*rs*g3v[nt]+be3v[nt];
        }
      }
    }
  }
  __syncthreads();

  // ---- classifier: wave w = kt chunk [400w,400w+400); ksub = l>>4 (100 kt each);
  // lane handles 4 classes (cg = l&15, classes 4cg..4cg+3; cg==15 duplicates 14, discarded)
  {
    int ksub = l>>4, cg = l&15;
    int cgc = (cg<15)?cg:14;
    int ktbase = w*400 + ksub*100;
    float a0=0.f,a1=0.f,a2=0.f,a3=0.f;
    for(int i=0;i<100;i++){
      int kt = ktbase + i;
      float4 h = h3m4[kt];
      const uint4* q = (const uint4*)(Wcp4 + (size_t)(kt*15+cgc)*16);
      uint4 wa = q[0], wb = q[1];
      half2v hA0 = pkh2(h.x, h.y);
      half2v hA1 = pkh2(h.z, h.w);
      a0 = __builtin_amdgcn_fdot2(hA0, u2h2(wa.x), a0, false);
      a0 = __builtin_amdgcn_fdot2(hA1, u2h2(wb.x), a0, false);
      a1 = __builtin_amdgcn_fdot2(hA0, u2h2(wa.y), a1, false);
      a1 = __builtin_amdgcn_fdot2(hA1, u2h2(wb.y), a1, false);
      a2 = __builtin_amdgcn_fdot2(hA0, u2h2(wa.z), a2, false);
      a2 = __builtin_amdgcn_fdot2(hA1, u2h2(wb.z), a2, false);
      a3 = __builtin_amdgcn_fdot2(hA0, u2h2(wa.w), a3, false);
      a3 = __builtin_amdgcn_fdot2(hA1, u2h2(wb.w), a3, false);
    }
    // reduce across the 4 ksub groups (lanes l^16, l^32)
    a0 += __shfl_xor(a0,16,64); a0 += __shfl_xor(a0,32,64);
    a1 += __shfl_xor(a1,16,64); a1 += __shfl_xor(a1,32,64);
    a2 += __shfl_xor(a2,16,64); a2 += __shfl_xor(a2,32,64);
    a3 += __shfl_xor(a3,16,64); a3 += __shfl_xor(a3,32,64);
    if(l<15){
      cs[w*60 + l*4 + 0] = a0;
      cs[w*60 + l*4 + 1] = a1;
      cs[w*60 + l*4 + 2] = a2;
      cs[w*60 + l*4 + 3] = a3;
    }
  }
  __syncthreads();
  if(t<60){
    float v = cs[t]+cs[60+t]+cs[120+t]+cs[180+t] + bc[t];
    stout(out, bid*NC+t, isbf, v);
  }
}

// ---- kernel 4: pred[b,c] = mean over 90 rows of block_mean
__global__ void k4_pred(const void* bm, const int* flagp, void* out){
  int b = blockIdx.x, t = threadIdx.x;
  int isbf = flagp[0];
  if(t<NC){
    float acc=0.f;
    for(int r=0;r<90;r++) acc += ldin(bm, (b*90+r)*NC+t, isbf);
    stout(out, NROW*NC + b*NC + t, isbf, acc*(1.f/90.f));
  }
}

extern "C" void kernel_launch(void* const* d_in, const int* in_sizes, int n_in,
                              void* d_out, int out_size, void* d_ws, size_t ws_size,
                              hipStream_t stream){
  const void* x   = d_in[0];
  const void* adj = d_in[1];
  char* ws = (char*)d_ws;
  int*     flagp = (int*)ws;
  float*   M     = (float*)(ws + WS_M_OFF);
  float*   pw    = (float*)(ws + WS_PW_OFF);
  half_t*  W3bf  = (half_t*)(ws + WS_W3BF_OFF);
  half_t*  W2bf  = (half_t*)(ws + WS_W2BF_OFF);
  half_t*  Wcp4  = (half_t*)(ws + WS_WCP_OFF);

  k0_prep<<<1,256,0,stream>>>(x, adj, flagp, M);
  k1_repack<<<(P_TOT+255)/256,256,0,stream>>>(d_in[2],d_in[3],d_in[4],d_in[5],
                                              d_in[6],d_in[7],d_in[8],d_in[9],
                                              d_in[11],d_in[12],d_in[13],
                                              d_in[15], flagp, pw);
  k1b_packw3<<<96,256,0,stream>>>(d_in[10], flagp, W3bf);
  k1c_packw2<<<20,256,0,stream>>>(d_in[6], flagp, W2bf);
  k2_fold<<<1500,256,0,stream>>>(d_in[14], M, flagp, Wcp4);
  k3_main<<<NROW,256,0,stream>>>(x, pw, W3bf, W2bf, (const unsigned short*)Wcp4,
                                 flagp, d_out);
  k4_pred<<<BB,64,0,stream>>>(d_out, flagp, d_out);
}

// Round 9
// 169.525 us; speedup vs baseline: 3.3235x; 1.0378x over previous
//
#include <hip/hip_runtime.h>
#include <hip/hip_bf16.h>

typedef __hip_bfloat16 bf16t;
typedef _Float16 half_t;
typedef __attribute__((ext_vector_type(2))) _Float16 half2v;
typedef __attribute__((ext_vector_type(8))) _Float16 half8v;
typedef __attribute__((ext_vector_type(4))) float f32x4;
typedef unsigned int uint32;

#define BB   32
#define NBB  10
#define JJ   25
#define NC   60
#define NROW (BB*NBB*3*3)
#define EPSF 1e-5f
#define ALPHA 0.2f
#define DEG  4

// ws layout (bytes), footprint within proven 869376:
//  0     : int flag
//  256   : float M[625]
//  4096  : float pw[5796]
//  28672 : f16 W3bf[24576]  [ct(16)][kt(3)][lane][8]
//  77824 : f16 W2bf[5120]   [ct(5)][kt(2)][lane][8]
//  88064 : f16 W1bf[1536]   [ct(3)][lane][8]
//  101376: f16 Wcp4[384000] [kt(1600)][cg(15)][p(2)][cl(4)][e(2)]
#define WS_M_OFF    256
#define WS_PW_OFF   4096
#define WS_W3BF_OFF 28672
#define WS_W2BF_OFF 77824
#define WS_W1BF_OFF 88064
#define WS_WCP_OFF  101376

// pw float offsets
#define P_W1  0
#define P_B1  1152
#define P_G1  1200
#define P_BE1 1248
#define P_W2  1296
#define P_B2  4752
#define P_G2  4824
#define P_BE2 4896
#define P_B3  4968
#define P_G3  5224
#define P_BE3 5480
#define P_BC  5736
#define P_TOT 5796
// k1_all ranges
#define R_W3E (P_TOT+24576)      // 30372
#define R_W2E (R_W3E+5120)       // 35492
#define R_W1E (R_W2E+1536)       // 37028

// k3 LDS byte offsets (total 38848 B -> 4 blocks/CU)
#define LB_H3H 0        // ushort[6400] f16 h3 (25 rows x 256)
#define LB_A1  12800    // f16 [64][72]
#define LB_A2  22016    // f16 [64][104]; x f16 [64][40] overlays first 5120 B
#define LB_STW 35328    // float[512]
#define LB_ST2 37376    // float[128]
#define LB_CS  37888    // float[240]
#define LDS_FTOT 9712   // floats

__device__ __forceinline__ float ldin(const void* p, int i, int isbf){
  return isbf ? __bfloat162float(((const bf16t*)p)[i]) : ((const float*)p)[i];
}
__device__ __forceinline__ void stout(void* p, int i, int isbf, float v){
  if(isbf) ((bf16t*)p)[i] = __float2bfloat16(v);
  else     ((float*)p)[i] = v;
}
__device__ __forceinline__ half2v u2h2(uint32 u){
  half2v h; __builtin_memcpy(&h,&u,4); return h;
}

// ---- kernel 0: dtype detect + M = alpha*I + (1-alpha)/deg * sum_k A^k
__global__ void k0_prep(const void* x, const void* adj, int* flagp, float* M){
  __shared__ float A[625], P[625], Q[625], Ss[625];
  __shared__ int cnt, flg;
  int t = threadIdx.x;
  if(t==0) cnt = 0;
  __syncthreads();
  {
    const unsigned short* xb = (const unsigned short*)x;
    unsigned short u = xb[2*t];
    int e = (u>>7)&0xFF;
    if(e>=100 && e<=141) atomicAdd(&cnt,1);
  }
  __syncthreads();
  if(t==0){ flg = (cnt>=160)?1:0; flagp[0]=flg; }
  __syncthreads();
  int isbf = flg;
  for(int i=t;i<625;i+=256){ float a=ldin(adj,i,isbf); A[i]=a; P[i]=a; Ss[i]=a; }
  __syncthreads();
  for(int d=1; d<DEG; ++d){
    for(int o=t;o<625;o+=256){
      int i=o/25, j=o%25; float acc=0.f;
      for(int k=0;k<25;k++) acc += A[i*25+k]*P[k*25+j];
      Q[o]=acc;
    }
    __syncthreads();
    for(int o=t;o<625;o+=256){ P[o]=Q[o]; Ss[o]+=Q[o]; }
    __syncthreads();
  }
  const float coef = (1.0f-ALPHA)/(float)DEG;
  for(int o=t;o<625;o+=256){
    int i=o/25, j=o%25;
    M[o] = (i==j ? ALPHA : 0.0f) + coef*Ss[o];
  }
}

// ---- kernel 1: all param repack/pack (pw fp32, W3/W2/W1 f16 fragments)
__global__ void k1_all(const void* W1,const void* b1,const void* g1,const void* be1,
                       const void* W2,const void* b2,const void* g2,const void* be2,
                       const void* W3,const void* b3,const void* g3,const void* be3,
                       const void* bc, const int* flagp,
                       float* pw, half_t* W3bf, half_t* W2bf, half_t* W1bf){
  int isbf = flagp[0];
  int o = blockIdx.x*256 + threadIdx.x;
  if(o < P_TOT){
    const void* src; int loc;
    if      (o < P_B1 ) { src=W1;  loc=o;        }
    else if (o < P_G1 ) { src=b1;  loc=o-P_B1;   }
    else if (o < P_BE1) { src=g1;  loc=o-P_G1;   }
    else if (o < P_W2 ) { src=be1; loc=o-P_BE1;  }
    else if (o < P_B2 ) { src=W2;  loc=o-P_W2;   }
    else if (o < P_G2 ) { src=b2;  loc=o-P_B2;   }
    else if (o < P_BE2) { src=g2;  loc=o-P_G2;   }
    else if (o < P_B3 ) { src=be2; loc=o-P_BE2;  }
    else if (o < P_G3 ) { src=b3;  loc=o-P_B3;   }
    else if (o < P_BE3) { src=g3;  loc=o-P_G3;   }
    else if (o < P_BC ) { src=be3; loc=o-P_BE3;  }
    else                { src=bc;  loc=o-P_BC;   }
    pw[o] = ldin(src, loc, isbf);
  } else if(o < R_W3E){
    int o2 = o - P_TOT;
    int ct = o2/1536, rem = o2 - ct*1536;
    int kt = rem/512, rem2 = rem - kt*512;
    int l = rem2>>3, j = rem2&7;
    int k = kt*32 + ((l>>4)<<3) + j;
    int col = (ct<<4) + (l&15);
    float v = (k<72) ? ldin(W3, k*256+col, isbf) : 0.f;
    W3bf[o2] = (half_t)v;
  } else if(o < R_W2E){
    int o2 = o - R_W3E;
    int ct = o2/1024, rem = o2 - ct*1024;
    int kt = rem/512, rem2 = rem - kt*512;
    int l = rem2>>3, j = rem2&7;
    int k = kt*32 + ((l>>4)<<3) + j;
    int col = (ct<<4) + (l&15);
    float v = (k<48 && col<72) ? ldin(W2, k*72+col, isbf) : 0.f;
    W2bf[o2] = (half_t)v;
  } else if(o < R_W1E){
    int o2 = o - R_W2E;
    int ct = o2/512, rem2 = o2 - ct*512;
    int l = rem2>>3, j = rem2&7;
    int k = ((l>>4)<<3) + j;                 // K=32, kt=0
    int col = (ct<<4) + (l&15);
    float v = (k<24) ? ldin(W1, k*48+col, isbf) : 0.f;
    W1bf[o2] = (half_t)v;
  }
}

// ---- kernel 2: fold SGC mix into classifier weights, f16, dot2-tiled
__global__ void k2_fold(const void* Wc, const float* M, const int* flagp, half_t* Wcp4){
  int isbf = flagp[0];
  int o = blockIdx.x*256 + threadIdx.x;
  if(o >= 384000) return;
  int grp = o>>4, hw = o&15;
  int kt = grp/15, cg = grp - kt*15;
  int p = hw>>3, cl = (hw>>1)&3, e = hw&1;
  int fl = kt*4 + 2*p + e;
  int j = fl>>8, f = fl&255;
  int c = cg*4 + cl;
  float acc = 0.f;
  for(int i=0;i<25;i++) acc += M[i*25+j]*ldin(Wc, (i*256+f)*60 + c, isbf);
  Wcp4[o] = (half_t)(0.5f*acc);
}

// ---- kernel 3: MFMA1+MFMA2+MFMA3 (f16) + wave-local LNs -> s-mean(f16) -> dot2 classifier
__global__ __launch_bounds__(256) void k3_main(const void* x, const float* pw,
                                               const half_t* W3bf_, const half_t* W2bf_,
                                               const half_t* W1bf_,
                                               const unsigned short* Wcp4,
                                               const int* flagp, void* out){
  __shared__ float sm[LDS_FTOT];
  char* smb = (char*)sm;
  half_t* H3H = (half_t*)(smb + LB_H3H);            // f16 [25][256]
  half_t* A1h = (half_t*)(smb + LB_A1);             // f16 [64][72]
  half_t* A2h = (half_t*)(smb + LB_A2);             // f16 [64][104]
  half_t* XH  = A2h;                                // f16 [64][40] overlay
  float*  stw = (float*)(smb + LB_STW);
  float*  st2 = (float*)(smb + LB_ST2);
  float*  cs  = (float*)(smb + LB_CS);
  uint32* A1w = (uint32*)A1h;
  uint32* XHw = (uint32*)XH;
  const unsigned short* W3u = (const unsigned short*)W3bf_;
  const unsigned short* W2u = (const unsigned short*)W2bf_;
  const unsigned short* W1u = (const unsigned short*)W1bf_;

  int t = threadIdx.x, bid = blockIdx.x;
  int l = t&63, w = t>>6, cb = l&15, g4 = l>>4;
  int isbf = flagp[0];
  const float* b1=pw+P_B1;  const float* g1=pw+P_G1;  const float* be1=pw+P_BE1;
  const float* b2=pw+P_B2;  const float* g2=pw+P_G2;  const float* be2=pw+P_BE2;
  const float* b3=pw+P_B3;  const float* g3=pw+P_G3;  const float* be3=pw+P_BE3;
  const float* bc=pw+P_BC;

  // ---- init: stage x -> f16 [64][40]; zero pads (disjoint writes, one barrier)
  {
    int xoff = bid*1200;
    for(int i=t;i<1200;i+=256){
      float v = ldin(x, xoff+i, isbf);
      int r = i/24, c = i - r*24;
      XH[r*40+c] = (half_t)v;
    }
    if(t<256){ int r=t>>2, dc=12+(t&3); XHw[r*20+dc]=0; }          // x cols 24..31
    if(t<168){ int r=50+t/12, dc=t-(t/12)*12; XHw[r*20+dc]=0; }    // x rows 50..63 cols 0..23
    for(int o=t;o<512;o+=256){ int r=o>>3, dc=24+(o&7); A1w[r*36+dc]=0; } // A1 cols 48..63
  }
  __syncthreads();

  // ---- MFMA1: [64(50),48] = x[64,32] @ W1[32,48]; M-split (wave w rows 16w..16w+15)
  {
    f32x4 acc1[3];
    float g1v[3], be1v[3];
    #pragma unroll
    for(int ct=0;ct<3;ct++){
      int col = ct*16 + cb;
      float b = b1[col]; g1v[ct]=g1[col]; be1v[ct]=be1[col];
      acc1[ct][0]=b; acc1[ct][1]=b; acc1[ct][2]=b; acc1[ct][3]=b;
    }
    half8v a = *(const half8v*)(XH + (w*16 + cb)*40 + (g4<<3));
    #pragma unroll
    for(int ct=0;ct<3;ct++){
      half8v b = *(const half8v*)(W1u + (ct*64 + l)*8);
      acc1[ct] = __builtin_amdgcn_mfma_f32_16x16x32_f16(a, b, acc1[ct], 0,0,0);
    }
    // LN1 wave-local (48 cols), relu, write A1 f16
    #pragma unroll
    for(int r=0;r<4;r++){
      float s1 = acc1[0][r]+acc1[1][r]+acc1[2][r];
      float s2 = acc1[0][r]*acc1[0][r]+acc1[1][r]*acc1[1][r]+acc1[2][r]*acc1[2][r];
      #pragma unroll
      for(int d=1;d<16;d<<=1){ s1+=__shfl_xor(s1,d,64); s2+=__shfl_xor(s2,d,64); }
      float m = s1*(1.f/48.f);
      float var = s2*(1.f/48.f)-m*m;
      float rs = rsqrtf(var+EPSF);
      int row = w*16 + (g4<<2) + r;
      #pragma unroll
      for(int ct=0;ct<3;ct++){
        float val = (acc1[ct][r]-m)*rs*g1v[ct]+be1v[ct];
        A1h[row*72 + ct*16 + cb] = (half_t)fmaxf(val,0.f);
      }
    }
  }
  __syncthreads();

  // ---- MFMA2: [64,80(72)] = A1[64,64(48)] @ W2[64,80]; M-split
  {
    f32x4 acc2[5];
    #pragma unroll
    for(int ct=0;ct<5;ct++){
      int col = ct*16 + cb;
      float b = (col<72) ? b2[col] : 0.f;
      acc2[ct][0]=b; acc2[ct][1]=b; acc2[ct][2]=b; acc2[ct][3]=b;
    }
    #pragma unroll
    for(int kt=0;kt<2;kt++){
      half8v a = *(const half8v*)(A1h + (w*16 + cb)*72 + kt*32 + (g4<<3));
      #pragma unroll
      for(int ct=0;ct<5;ct++){
        half8v b = *(const half8v*)(W2u + ((ct*2+kt)*64 + l)*8);
        acc2[ct] = __builtin_amdgcn_mfma_f32_16x16x32_f16(a, b, acc2[ct], 0,0,0);
      }
    }
    int valid4 = (cb<8);
    #pragma unroll
    for(int r=0;r<4;r++){
      float s1 = acc2[0][r]+acc2[1][r]+acc2[2][r]+acc2[3][r] + (valid4?acc2[4][r]:0.f);
      float s2 = acc2[0][r]*acc2[0][r]+acc2[1][r]*acc2[1][r]
               + acc2[2][r]*acc2[2][r]+acc2[3][r]*acc2[3][r]
               + (valid4?acc2[4][r]*acc2[4][r]:0.f);
      #pragma unroll
      for(int d=1;d<16;d<<=1){ s1+=__shfl_xor(s1,d,64); s2+=__shfl_xor(s2,d,64); }
      float m = s1*(1.f/72.f);
      float var = s2*(1.f/72.f)-m*m;
      float rs = rsqrtf(var+EPSF);
      int grow = w*16 + (g4<<2) + r;
      #pragma unroll
      for(int ct=0;ct<5;ct++){
        int col = ct*16 + cb;
        if(ct<4 || valid4){
          float val = (acc2[ct][r]-m)*rs*g2[col]+be2[col];
          A2h[grow*104+col] = (half_t)fmaxf(val,0.f);
        }
      }
    }
    // zero A2 k-pad cols 72..95 for own 16 rows (dwords 36..47 of 52)
    uint32* A2w = (uint32*)A2h;
    for(int o=l;o<192;o+=64){ int rr = w*16 + o/12, dc = 36 + (o - (o/12)*12); A2w[rr*52+dc]=0; }
  }
  __syncthreads();

  // ---- MFMA3: [64(50),96(72)] @ [96,256]; N-split (wave w cols 64w..64w+63)
  f32x4 acc[4][4];
  float g3v[4], be3v[4];
  {
    #pragma unroll
    for(int nt=0;nt<4;nt++){
      int col = w*64 + nt*16 + cb;
      float b3c = b3[col];
      g3v[nt]=g3[col]; be3v[nt]=be3[col];
      #pragma unroll
      for(int mt=0;mt<4;mt++){ acc[mt][nt][0]=b3c; acc[mt][nt][1]=b3c; acc[mt][nt][2]=b3c; acc[mt][nt][3]=b3c; }
    }
    #pragma unroll
    for(int kt=0;kt<3;kt++){
      half8v a[4];
      #pragma unroll
      for(int mt=0;mt<4;mt++)
        a[mt] = *(const half8v*)(A2h + (mt*16+cb)*104 + kt*32 + (g4<<3));
      #pragma unroll
      for(int nt=0;nt<4;nt++){
        int ct = w*4 + nt;
        half8v b = *(const half8v*)(W3u + ((ct*3+kt)*64 + l)*8);
        #pragma unroll
        for(int mt=0;mt<4;mt++)
          acc[mt][nt] = __builtin_amdgcn_mfma_f32_16x16x32_f16(a[mt], b, acc[mt][nt], 0,0,0);
      }
    }
  }
  // LN3 stats: 16-lane shfl + cross-wave combine
  #pragma unroll
  for(int mt=0;mt<4;mt++){
    #pragma unroll
    for(int r=0;r<4;r++){
      float s1 = acc[mt][0][r]+acc[mt][1][r]+acc[mt][2][r]+acc[mt][3][r];
      float s2 = acc[mt][0][r]*acc[mt][0][r]+acc[mt][1][r]*acc[mt][1][r]
               + acc[mt][2][r]*acc[mt][2][r]+acc[mt][3][r]*acc[mt][3][r];
      #pragma unroll
      for(int d=1;d<16;d<<=1){ s1+=__shfl_xor(s1,d,64); s2+=__shfl_xor(s2,d,64); }
      if(cb==0){
        int row = mt*16 + (g4<<2) + r;
        stw[row*8 + w*2]   = s1;
        stw[row*8 + w*2+1] = s2;
      }
    }
  }
  __syncthreads();
  if(t<64){
    float S1 = stw[t*8+0]+stw[t*8+2]+stw[t*8+4]+stw[t*8+6];
    float S2 = stw[t*8+1]+stw[t*8+3]+stw[t*8+5]+stw[t*8+7];
    float m = S1*(1.f/256.f);
    float var = S2*(1.f/256.f)-m*m;
    st2[2*t]=m; st2[2*t+1]=rsqrtf(var+EPSF);
  }
  __syncthreads();
  // pass A: rows 0..24 -> H3H = f16(ln)
  #pragma unroll
  for(int mt=0;mt<2;mt++){
    #pragma unroll
    for(int r=0;r<4;r++){
      int row = mt*16 + (g4<<2) + r;
      if(row<25){
        float m=st2[2*row], rs=st2[2*row+1];
        #pragma unroll
        for(int nt=0;nt<4;nt++){
          int col = w*64 + nt*16 + cb;
          H3H[row*256+col] = (half_t)((acc[mt][nt][r]-m)*rs*g3v[nt]+be3v[nt]);
        }
      }
    }
  }
  __syncthreads();
  // pass B: rows 25..49 -> H3H += f16(ln)
  #pragma unroll
  for(int mt=1;mt<4;mt++){
    #pragma unroll
    for(int r=0;r<4;r++){
      int row = mt*16 + (g4<<2) + r;
      if(row>=25 && row<50){
        float m=st2[2*row], rs=st2[2*row+1];
        int jrow = row-25;
        #pragma unroll
        for(int nt=0;nt<4;nt++){
          int col = w*64 + nt*16 + cb;
          float v = (float)H3H[jrow*256+col] + (acc[mt][nt][r]-m)*rs*g3v[nt]+be3v[nt];
          H3H[jrow*256+col] = (half_t)v;
        }
      }
    }
  }
  __syncthreads();

  // ---- classifier: wave w = kt chunk [400w..400w+400); ksub = g4 (100 kt);
  // lane: 4 classes (cg=cb; cg==15 duplicates 14, discarded)
  {
    int cgc = (cb<15)?cb:14;
    int ktbase = w*400 + g4*100;
    const unsigned short* H3u = (const unsigned short*)H3H;
    float a0=0.f,a1=0.f,a2=0.f,a3=0.f;
    for(int i=0;i<100;i++){
      int kt = ktbase + i;
      uint2 hq = *(const uint2*)(H3u + kt*4);      // 4 f16 of h3
      const uint4* q = (const uint4*)(Wcp4 + (size_t)(kt*15+cgc)*16);
      uint4 wa = q[0], wb = q[1];
      half2v h01 = u2h2(hq.x), h23 = u2h2(hq.y);
      a0 = __builtin_amdgcn_fdot2(h01, u2h2(wa.x), a0, false);
      a0 = __builtin_amdgcn_fdot2(h23, u2h2(wb.x), a0, false);
      a1 = __builtin_amdgcn_fdot2(h01, u2h2(wa.y), a1, false);
      a1 = __builtin_amdgcn_fdot2(h23, u2h2(wb.y), a1, false);
      a2 = __builtin_amdgcn_fdot2(h01, u2h2(wa.z), a2, false);
      a2 = __builtin_amdgcn_fdot2(h23, u2h2(wb.z), a2, false);
      a3 = __builtin_amdgcn_fdot2(h01, u2h2(wa.w), a3, false);
      a3 = __builtin_amdgcn_fdot2(h23, u2h2(wb.w), a3, false);
    }
    a0 += __shfl_xor(a0,16,64); a0 += __shfl_xor(a0,32,64);
    a1 += __shfl_xor(a1,16,64); a1 += __shfl_xor(a1,32,64);
    a2 += __shfl_xor(a2,16,64); a2 += __shfl_xor(a2,32,64);
    a3 += __shfl_xor(a3,16,64); a3 += __shfl_xor(a3,32,64);
    if(l<15){
      cs[w*60 + l*4 + 0] = a0;
      cs[w*60 + l*4 + 1] = a1;
      cs[w*60 + l*4 + 2] = a2;
      cs[w*60 + l*4 + 3] = a3;
    }
  }
  __syncthreads();
  if(t<60){
    float v = cs[t]+cs[60+t]+cs[120+t]+cs[180+t] + bc[t];
    stout(out, bid*NC+t, isbf, v);
  }
}

// ---- kernel 4: pred[b,c] = mean over 90 rows of block_mean
__global__ void k4_pred(const void* bm, const int* flagp, void* out){
  int b = blockIdx.x, t = threadIdx.x;
  int isbf = flagp[0];
  if(t<NC){
    float acc=0.f;
    for(int r=0;r<90;r++) acc += ldin(bm, (b*90+r)*NC+t, isbf);
    stout(out, NROW*NC + b*NC + t, isbf, acc*(1.f/90.f));
  }
}

extern "C" void kernel_launch(void* const* d_in, const int* in_sizes, int n_in,
                              void* d_out, int out_size, void* d_ws, size_t ws_size,
                              hipStream_t stream){
  const void* x   = d_in[0];
  const void* adj = d_in[1];
  char* ws = (char*)d_ws;
  int*     flagp = (int*)ws;
  float*   M     = (float*)(ws + WS_M_OFF);
  float*   pw    = (float*)(ws + WS_PW_OFF);
  half_t*  W3bf  = (half_t*)(ws + WS_W3BF_OFF);
  half_t*  W2bf  = (half_t*)(ws + WS_W2BF_OFF);
  half_t*  W1bf  = (half_t*)(ws + WS_W1BF_OFF);
  half_t*  Wcp4  = (half_t*)(ws + WS_WCP_OFF);

  k0_prep<<<1,256,0,stream>>>(x, adj, flagp, M);
  k1_all<<<(R_W1E+255)/256,256,0,stream>>>(d_in[2],d_in[3],d_in[4],d_in[5],
                                           d_in[6],d_in[7],d_in[8],d_in[9],
                                           d_in[10],d_in[11],d_in[12],d_in[13],
                                           d_in[15], flagp, pw, W3bf, W2bf, W1bf);
  k2_fold<<<1500,256,0,stream>>>(d_in[14], M, flagp, Wcp4);
  k3_main<<<NROW,256,0,stream>>>(x, pw, W3bf, W2bf, W1bf,
                                 (const unsigned short*)Wcp4, flagp, d_out);
  k4_pred<<<BB,64,0,stream>>>(d_out, flagp, d_out);
}